// Round 7
// baseline (532.154 us; speedup 1.0000x reference)
//
#include <hip/hip_runtime.h>

// BiLSTM (diagonal, PixelRNN-style) on MI355X.
// R6: 1 step/launch (the proven-best structure, R0) with the step kernel
// rebuilt for occupancy + traffic: 1024 blocks (1 row x full N each, 4 blocks/CU,
// 16 waves/CU), B-fragments streamed per-kk to stay <=128 VGPR, lc in fp16
// transposed [c][p] (vector 8B r/w), hmap transposed [c][p] ushort4 (16B loads).

using bf16   = __bf16;
using bf16x8 = __attribute__((ext_vector_type(8))) __bf16;
using f32x4  = __attribute__((ext_vector_type(4))) float;
using u16x8  = __attribute__((ext_vector_type(8))) unsigned short;
using f16    = _Float16;
using f16x4  = __attribute__((ext_vector_type(4))) _Float16;

__device__ __forceinline__ float sigf(float x) {
  return __builtin_amdgcn_rcpf(1.0f + __expf(-x));
}
__device__ __forceinline__ float tanh_fast(float x) {
  return 2.0f * __builtin_amdgcn_rcpf(1.0f + __expf(-2.0f * x)) - 1.0f;
}
__device__ __forceinline__ bf16x8 bzero8() {
  bf16x8 v;
#pragma unroll
  for (int e = 0; e < 8; ++e) v[e] = (bf16)0.0f;
  return v;
}
__device__ __forceinline__ unsigned short f2bu(float f) {
  bf16 b = (bf16)f;
  return __builtin_bit_cast(unsigned short, b);
}
__device__ __forceinline__ float bu2f(unsigned short u) {
  return __uint_as_float(((unsigned)u) << 16);
}

// ---------------- prep: weights -> bf16, [n][k] layouts ----------------
__global__ void prep_kernel(const float* __restrict__ w_i2s,
                            const float* __restrict__ w_left,
                            const float* __restrict__ w_right,
                            const float* __restrict__ w_skip,
                            bf16* __restrict__ WnI, bf16* __restrict__ WnL,
                            bf16* __restrict__ WnR, bf16* __restrict__ WnS) {
  int t = blockIdx.x * 256 + threadIdx.x;
  if (t < 32768) {
    WnI[t] = (bf16)w_i2s[t];  // [256][128] o-major == desired [n][k]
    int o = t >> 7, k = t & 127;
    // k<64: tap0 (h-1, w+-1) -> w[:,:,0]; k>=64: tap1 (h, w+-1) -> w[:,:,1]
    int src = (k < 64) ? (o * 128 + k * 2) : (o * 128 + (k - 64) * 2 + 1);
    WnL[t] = (bf16)w_left[src];
    WnR[t] = (bf16)w_right[src];
    if (t < 8192) WnS[t] = (bf16)w_skip[t];  // [128][64]
  }
}

// ------- hmapT = pack(x @ w_i2s^T) : [c][p] ushort4 (4 gates, bf16 bits) -------
__global__ __launch_bounds__(256, 2)
void hmap_kernel(const float* __restrict__ x, const bf16* __restrict__ Wn,
                 ushort4* __restrict__ hmapT) {
  __shared__ __align__(16) bf16 At[64 * 128];  // XOR-swizzled
  const int tile = blockIdx.x;  // 256 tiles: 64 px each (2 rows of one batch)
  const int b = tile >> 4, h0 = (tile & 15) << 1;
  const int t = threadIdx.x;
  const float* xb = x + (size_t)(b * 128) * 1024 + h0 * 32;
#pragma unroll
  for (int i = 0; i < 8; ++i) {
    int idx = t + 256 * i;          // [0,2048)
    int cc = idx >> 4, m4 = idx & 15;
    f32x4 v = *(const f32x4*)(xb + (size_t)cc * 1024 + m4 * 4);
#pragma unroll
    for (int e = 0; e < 4; ++e) {
      int m = m4 * 4 + e;
      int kb = (cc * 2) ^ ((m & 7) << 4);
      *(bf16*)((char*)At + m * 256 + kb) = (bf16)v[e];
    }
  }
  __syncthreads();
  const int wv = t >> 6, l = t & 63;
  const int l15 = l & 15, lq = l >> 4;
  const int c = wv * 16 + l15;
  bf16x8 bfrag[4][4];
#pragma unroll
  for (int q = 0; q < 4; ++q)
#pragma unroll
    for (int kk = 0; kk < 4; ++kk)
      bfrag[q][kk] = *(const bf16x8*)(Wn + (q * 64 + c) * 128 + kk * 32 + lq * 8);
  f32x4 acc[4][4];
  const f32x4 fz = {0.f, 0.f, 0.f, 0.f};
#pragma unroll
  for (int ms = 0; ms < 4; ++ms)
#pragma unroll
    for (int q = 0; q < 4; ++q) acc[ms][q] = fz;
#pragma unroll
  for (int kk = 0; kk < 4; ++kk) {
#pragma unroll
    for (int ms = 0; ms < 4; ++ms) {
      int m = ms * 16 + l15;
      int kb = ((kk * 32 + lq * 8) * 2) ^ ((m & 7) << 4);
      bf16x8 a = *(const bf16x8*)((const char*)At + m * 256 + kb);
#pragma unroll
      for (int q = 0; q < 4; ++q)
        acc[ms][q] =
            __builtin_amdgcn_mfma_f32_16x16x32_bf16(a, bfrag[q][kk], acc[ms][q], 0, 0, 0);
    }
  }
  const int pix0 = tile * 64;
#pragma unroll
  for (int ms = 0; ms < 4; ++ms)
#pragma unroll
    for (int j = 0; j < 4; ++j) {
      int p = pix0 + ms * 16 + lq * 4 + j;
      ushort4 hv;
      hv.x = f2bu(acc[ms][0][j]);
      hv.y = f2bu(acc[ms][1][j]);
      hv.z = f2bu(acc[ms][2][j]);
      hv.w = f2bu(acc[ms][3][j]);
      hmapT[(size_t)c * 16384 + p] = hv;
    }
}

// ---------------- one scan step ----------------
// 1024 blocks: blk = b*64 + h*2 + stream. Block = 1 row (32 px) x full N(256).
// 4 waves split channels (c = wv*16+l15); each wave: 2 m-tiles x 4 gates.
// A-tile (32m x 128k) staged once in LDS; B streamed per-kk (VGPR <= 128).
__global__ __launch_bounds__(256, 4)
void step_kernel(const bf16* __restrict__ lhLin, bf16* __restrict__ lhLout,
                 const bf16* __restrict__ lhRin, bf16* __restrict__ lhRout,
                 f16* __restrict__ lcTL, f16* __restrict__ lcTR,
                 const ushort4* __restrict__ hmapT,
                 const bf16* __restrict__ WnL, const bf16* __restrict__ WnR,
                 const float* __restrict__ bL, const float* __restrict__ bR) {
  __shared__ __align__(16) bf16 At[32 * 128];  // 8 KB, XOR-swizzled
  const int blk = blockIdx.x;
  const bool right = (blk & 1) != 0;
  const int h = (blk >> 1) & 31;
  const int b = blk >> 6;
  const bf16* __restrict__ lin = right ? lhRin : lhLin;
  bf16* __restrict__ lout = right ? lhRout : lhLout;
  f16* __restrict__ lcT = right ? lcTR : lcTL;
  const bf16* __restrict__ Wn = right ? WnR : WnL;
  const float* __restrict__ bias = right ? bR : bL;
  const int dw = right ? 1 : -1;
  const int t = threadIdx.x;
  const int wv = t >> 6, l = t & 63, l15 = l & 15, lq = l >> 4;
  const int c = wv * 16 + l15;  // channel this lane owns (gate-interleaved N)

  // ---- stage A: [m=w][k]; k<64 = lh(h-1,w+dw), k>=64 = lh(h,w+dw); OOB -> 0
#pragma unroll
  for (int i = 0; i < 2; ++i) {
    int idx = t + 256 * i;  // [0,512)
    int tap = idx >> 8, rem = idx & 255, m = rem >> 3, c8 = rem & 7;
    int wsrc = m + dw, hsrc = h - 1 + tap;
    bf16x8 v = bzero8();
    if ((unsigned)wsrc < 32u && hsrc >= 0)
      v = *(const bf16x8*)(lin + (size_t)((b * 32 + hsrc) * 32 + wsrc) * 64 + c8 * 8);
    int kb = (tap * 128 + c8 * 16) ^ ((m & 7) << 4);
    *(bf16x8*)((char*)At + m * 256 + kb) = v;
  }

  // ---- prologue gathers (independent of LDS; overlap with staging) ----
  const int pb0 = b * 1024 + h * 32;
  float bq[4];
#pragma unroll
  for (int q = 0; q < 4; ++q) bq[q] = bias[q * 64 + c];
  u16x8 hm8[2][2];
  f16x4 lc4[2];
  const ushort4* hrow = hmapT + (size_t)c * 16384;
  const f16* lcrow = lcT + (size_t)c * 16384;
#pragma unroll
  for (int ms = 0; ms < 2; ++ms) {
    int pw = pb0 + ms * 16 + lq * 4;
    hm8[ms][0] = *(const u16x8*)(hrow + pw);       // px j=0,1 (gates packed)
    hm8[ms][1] = *(const u16x8*)(hrow + pw + 2);   // px j=2,3
    lc4[ms] = *(const f16x4*)(lcrow + pw);
  }
  __syncthreads();

  // ---- GEMM: A from LDS, B streamed per-kk ----
  f32x4 acc[2][4];
  const f32x4 fz = {0.f, 0.f, 0.f, 0.f};
#pragma unroll
  for (int ms = 0; ms < 2; ++ms)
#pragma unroll
    for (int q = 0; q < 4; ++q) acc[ms][q] = fz;
#pragma unroll
  for (int kk = 0; kk < 4; ++kk) {
    bf16x8 bf[4];
#pragma unroll
    for (int q = 0; q < 4; ++q)
      bf[q] = *(const bf16x8*)(Wn + (q * 64 + c) * 128 + kk * 32 + lq * 8);
#pragma unroll
    for (int ms = 0; ms < 2; ++ms) {
      int m = ms * 16 + l15;
      int kb = ((kk * 32 + lq * 8) * 2) ^ ((m & 7) << 4);
      bf16x8 a = *(const bf16x8*)((const char*)At + m * 256 + kb);
#pragma unroll
      for (int q = 0; q < 4; ++q)
        acc[ms][q] =
            __builtin_amdgcn_mfma_f32_16x16x32_bf16(a, bf[q], acc[ms][q], 0, 0, 0);
    }
  }

  // ---- epilogue: gates; lc fp16 vector r/w; lh store ----
#pragma unroll
  for (int ms = 0; ms < 2; ++ms) {
    int pw = pb0 + ms * 16 + lq * 4;
    f16x4 lcn;
#pragma unroll
    for (int j = 0; j < 4; ++j) {
      u16x8 hm = hm8[ms][j >> 1];
      int e = (j & 1) * 4;
      float pre0 = acc[ms][0][j] + bu2f(hm[e + 0]) + bq[0];
      float pre1 = acc[ms][1][j] + bu2f(hm[e + 1]) + bq[1];
      float pre2 = acc[ms][2][j] + bu2f(hm[e + 2]) + bq[2];
      float pre3 = acc[ms][3][j] + bu2f(hm[e + 3]) + bq[3];
      float og = sigf(pre0), fg = sigf(pre1), ig = sigf(pre2), gg = sigf(pre3);
      float lcv = fg * (float)lc4[ms][j] + ig * gg;
      lcn[j] = (f16)lcv;
      lout[(size_t)(pw + j) * 64 + c] = (bf16)(og * tanh_fast(lcv));
    }
    *(f16x4*)(lcT + (size_t)c * 16384 + pw) = lcn;
  }
}

// ---------------- final: out = x + (lhL + shift_down(lhR)) @ w_skip^T + b ----------------
__global__ __launch_bounds__(256, 2)
void final_kernel(const float* __restrict__ x, const bf16* __restrict__ lhL,
                  const bf16* __restrict__ lhR, const bf16* __restrict__ Wn,
                  const float* __restrict__ b_skip, float* __restrict__ out) {
  __shared__ __align__(16) bf16 At[64 * 64];
  __shared__ __align__(16) float smemT[128 * 72];  // [o2][m], padded rows
  const int tile = blockIdx.x;
  const int b = tile >> 4, h0 = (tile & 15) << 1;
  const int t = threadIdx.x;
#pragma unroll
  for (int i = 0; i < 2; ++i) {
    int idx = t + 256 * i;  // [0,512)
    int m = idx >> 3, c8 = idx & 7;
    int h = h0 + (m >> 5), w = m & 31;
    size_t p = (size_t)(b * 32 + h) * 32 + w;
    bf16x8 vL = *(const bf16x8*)(lhL + p * 64 + c8 * 8);
    bf16x8 v;
    if (h > 0) {
      bf16x8 vR = *(const bf16x8*)(lhR + (p - 32) * 64 + c8 * 8);
#pragma unroll
      for (int e = 0; e < 8; ++e) v[e] = (bf16)((float)vL[e] + (float)vR[e]);
    } else {
      v = vL;
    }
    int kb = (c8 * 16) ^ ((m & 7) << 4);
    *(bf16x8*)((char*)At + m * 128 + kb) = v;
  }
  __syncthreads();
  const int wv = t >> 6, l = t & 63;
  const int l15 = l & 15, lq = l >> 4;
  const int c = wv * 16 + l15;
  bf16x8 bfrag[2][2];
#pragma unroll
  for (int q = 0; q < 2; ++q)
#pragma unroll
    for (int kk = 0; kk < 2; ++kk)
      bfrag[q][kk] = *(const bf16x8*)(Wn + (q * 64 + c) * 64 + kk * 32 + lq * 8);
  f32x4 acc[4][2];
  const f32x4 fz = {0.f, 0.f, 0.f, 0.f};
#pragma unroll
  for (int ms = 0; ms < 4; ++ms)
#pragma unroll
    for (int q = 0; q < 2; ++q) acc[ms][q] = fz;
#pragma unroll
  for (int kk = 0; kk < 2; ++kk) {
#pragma unroll
    for (int ms = 0; ms < 4; ++ms) {
      int m = ms * 16 + l15;
      int kb = ((kk * 32 + lq * 8) * 2) ^ ((m & 7) << 4);
      bf16x8 a = *(const bf16x8*)((const char*)At + m * 128 + kb);
#pragma unroll
      for (int q = 0; q < 2; ++q)
        acc[ms][q] =
            __builtin_amdgcn_mfma_f32_16x16x32_bf16(a, bfrag[q][kk], acc[ms][q], 0, 0, 0);
    }
  }
  float bsk[2];
#pragma unroll
  for (int q = 0; q < 2; ++q) bsk[q] = b_skip[q * 64 + c];
#pragma unroll
  for (int ms = 0; ms < 4; ++ms)
#pragma unroll
    for (int q = 0; q < 2; ++q)
#pragma unroll
      for (int j = 0; j < 4; ++j) {
        int m = ms * 16 + lq * 4 + j;
        int n = q * 64 + c;
        smemT[n * 72 + m] = acc[ms][q][j] + bsk[q];
      }
  __syncthreads();
  const float* xb = x + (size_t)(b * 128) * 1024 + h0 * 32;
  float* ob = out + (size_t)(b * 128) * 1024 + h0 * 32;
#pragma unroll
  for (int i = 0; i < 8; ++i) {
    int idx = t + 256 * i;  // [0,2048)
    int o2 = idx >> 4, m4 = idx & 15;
    f32x4 s = *(const f32x4*)(&smemT[o2 * 72 + m4 * 4]);
    f32x4 xv = *(const f32x4*)(xb + (size_t)o2 * 1024 + m4 * 4);
#pragma unroll
    for (int e = 0; e < 4; ++e) s[e] += xv[e];
    *(f32x4*)(ob + (size_t)o2 * 1024 + m4 * 4) = s;
  }
}

extern "C" void kernel_launch(void* const* d_in, const int* in_sizes, int n_in,
                              void* d_out, int out_size, void* d_ws, size_t ws_size,
                              hipStream_t stream) {
  const float* x       = (const float*)d_in[0];
  const float* w_i2s   = (const float*)d_in[1];
  const float* w_left  = (const float*)d_in[2];
  const float* b_left  = (const float*)d_in[3];
  const float* w_right = (const float*)d_in[4];
  const float* b_right = (const float*)d_in[5];
  const float* w_skip  = (const float*)d_in[6];
  const float* b_skip  = (const float*)d_in[7];
  float* out = (float*)d_out;
  char* ws = (char*)d_ws;

  // ws layout (bytes); total ~20.3 MB
  bf16*    lhL0  = (bf16*)(ws + 0x0000000);    // 2 MB (zeroed)
  bf16*    lhR0  = (bf16*)(ws + 0x0200000);    // 2 MB (zeroed)
  f16*     lcTL  = (f16*)(ws + 0x0400000);     // 2 MB (zeroed)
  f16*     lcTR  = (f16*)(ws + 0x0600000);     // 2 MB (zeroed)
  bf16*    lhL1  = (bf16*)(ws + 0x0800000);    // 2 MB
  bf16*    lhR1  = (bf16*)(ws + 0x0A00000);    // 2 MB
  ushort4* hmapT = (ushort4*)(ws + 0x0C00000); // 8 MB
  bf16*    WnI   = (bf16*)(ws + 0x1400000);    // 64 KB
  bf16*    WnL   = (bf16*)(ws + 0x1410000);
  bf16*    WnR   = (bf16*)(ws + 0x1420000);
  bf16*    WnS   = (bf16*)(ws + 0x1430000);

  // zero initial lh + lc (contiguous 8 MB)
  hipMemsetAsync(ws, 0, 0x0800000, stream);
  prep_kernel<<<128, 256, 0, stream>>>(w_i2s, w_left, w_right, w_skip, WnI, WnL, WnR, WnS);
  hmap_kernel<<<256, 256, 0, stream>>>(x, WnI, hmapT);
  for (int s = 0; s < 32; ++s) {
    bf16* liL = (s & 1) ? lhL1 : lhL0;
    bf16* loL = (s & 1) ? lhL0 : lhL1;
    bf16* liR = (s & 1) ? lhR1 : lhR0;
    bf16* loR = (s & 1) ? lhR0 : lhR1;
    step_kernel<<<1024, 256, 0, stream>>>(liL, loL, liR, loR, lcTL, lcTR,
                                          hmapT, WnL, WnR, b_left, b_right);
  }
  // after 32 steps (s=31 writes buffer 0), final state is in buffer 0
  final_kernel<<<256, 256, 0, stream>>>(x, lhL0, lhR0, WnS, b_skip, out);
}

// Round 8
// 186.518 us; speedup vs baseline: 2.8531x; 2.8531x over previous
//
#include <hip/hip_runtime.h>

// BiLSTM (diagonal, PixelRNN-style) on MI355X.
// R7: ONE persistent scan kernel, fence-free fine-grained neighbor sync.
// 512 blocks = 16 strips x (16 batches x 2 streams); block owns 2 rows.
// Per step: publish top row to an 8-deep LLC ring via RELAXED AGENT atomics
// (sc1, no L2 writeback -- R1's fences were the 85us/step killer), spin on a
// monotone flag, read 4KB halo from LLC. lc/weights/hmap in registers for all
// 32 steps; own rows in LDS double-buffer. Cross-XCD safe: LLC is the
// coherence point for agent atomics; same-XCD chain placement is only a
// latency heuristic (blk and blk+32 share blk%8).

using bf16   = __bf16;
using bf16x8 = __attribute__((ext_vector_type(8))) __bf16;
using f32x4  = __attribute__((ext_vector_type(4))) float;

#define SCOPE_AGENT __HIP_MEMORY_SCOPE_AGENT

__device__ __forceinline__ float sigf(float x) {
  return __builtin_amdgcn_rcpf(1.0f + __expf(-x));
}
__device__ __forceinline__ float tanh_fast(float x) {
  return 2.0f * __builtin_amdgcn_rcpf(1.0f + __expf(-2.0f * x)) - 1.0f;
}
__device__ __forceinline__ bf16x8 bzero8() {
  bf16x8 v;
#pragma unroll
  for (int e = 0; e < 8; ++e) v[e] = (bf16)0.0f;
  return v;
}
__device__ __forceinline__ unsigned short f2bu(float f) {
  bf16 b = (bf16)f;
  return __builtin_bit_cast(unsigned short, b);
}
__device__ __forceinline__ float bu2f(unsigned short u) {
  return __uint_as_float(((unsigned)u) << 16);
}

// ---------------- prep: weights -> bf16, [n][k] layouts ----------------
__global__ void prep_kernel(const float* __restrict__ w_i2s,
                            const float* __restrict__ w_left,
                            const float* __restrict__ w_right,
                            const float* __restrict__ w_skip,
                            bf16* __restrict__ WnI, bf16* __restrict__ WnL,
                            bf16* __restrict__ WnR, bf16* __restrict__ WnS) {
  int t = blockIdx.x * 256 + threadIdx.x;
  if (t < 32768) {
    WnI[t] = (bf16)w_i2s[t];  // [256][128] o-major == desired [n][k]
    int o = t >> 7, k = t & 127;
    // k<64: tap0 (h-1, w+-1) -> w[:,:,0]; k>=64: tap1 (h, w+-1) -> w[:,:,1]
    int src = (k < 64) ? (o * 128 + k * 2) : (o * 128 + (k - 64) * 2 + 1);
    WnL[t] = (bf16)w_left[src];
    WnR[t] = (bf16)w_right[src];
    if (t < 8192) WnS[t] = (bf16)w_skip[t];  // [128][64]
  }
}

// ------- hmap2 = pack(x @ w_i2s^T) : [p][c] ushort4 (4 gates, bf16 bits) -------
__global__ __launch_bounds__(256, 2)
void hmap_kernel(const float* __restrict__ x, const bf16* __restrict__ Wn,
                 ushort4* __restrict__ hmap2) {
  __shared__ __align__(16) bf16 At[64 * 128];  // XOR-swizzled
  const int tile = blockIdx.x;  // 256 tiles: 64 px each (2 rows of one batch)
  const int b = tile >> 4, h0 = (tile & 15) << 1;
  const int t = threadIdx.x;
  const float* xb = x + (size_t)(b * 128) * 1024 + h0 * 32;
#pragma unroll
  for (int i = 0; i < 8; ++i) {
    int idx = t + 256 * i;          // [0,2048)
    int cc = idx >> 4, m4 = idx & 15;
    f32x4 v = *(const f32x4*)(xb + (size_t)cc * 1024 + m4 * 4);
#pragma unroll
    for (int e = 0; e < 4; ++e) {
      int m = m4 * 4 + e;
      int kb = (cc * 2) ^ ((m & 7) << 4);
      *(bf16*)((char*)At + m * 256 + kb) = (bf16)v[e];
    }
  }
  __syncthreads();
  const int wv = t >> 6, l = t & 63;
  const int l15 = l & 15, lq = l >> 4;
  const int c = wv * 16 + l15;
  bf16x8 bfrag[4][4];
#pragma unroll
  for (int q = 0; q < 4; ++q)
#pragma unroll
    for (int kk = 0; kk < 4; ++kk)
      bfrag[q][kk] = *(const bf16x8*)(Wn + (q * 64 + c) * 128 + kk * 32 + lq * 8);
  f32x4 acc[4][4];
  const f32x4 fz = {0.f, 0.f, 0.f, 0.f};
#pragma unroll
  for (int ms = 0; ms < 4; ++ms)
#pragma unroll
    for (int q = 0; q < 4; ++q) acc[ms][q] = fz;
#pragma unroll
  for (int kk = 0; kk < 4; ++kk) {
#pragma unroll
    for (int ms = 0; ms < 4; ++ms) {
      int m = ms * 16 + l15;
      int kb = ((kk * 32 + lq * 8) * 2) ^ ((m & 7) << 4);
      bf16x8 a = *(const bf16x8*)((const char*)At + m * 256 + kb);
#pragma unroll
      for (int q = 0; q < 4; ++q)
        acc[ms][q] =
            __builtin_amdgcn_mfma_f32_16x16x32_bf16(a, bfrag[q][kk], acc[ms][q], 0, 0, 0);
    }
  }
  const int pix0 = tile * 64;
#pragma unroll
  for (int ms = 0; ms < 4; ++ms)
#pragma unroll
    for (int j = 0; j < 4; ++j) {
      int p = pix0 + ms * 16 + lq * 4 + j;
      ushort4 hv;
      hv.x = f2bu(acc[ms][0][j]);
      hv.y = f2bu(acc[ms][1][j]);
      hv.z = f2bu(acc[ms][2][j]);
      hv.w = f2bu(acc[ms][3][j]);
      hmap2[(size_t)p * 64 + c] = hv;
    }
}

// ---------------- persistent scan: all 32 steps ----------------
// blk = tl*32 + q, q = batch*2 + stream. Block owns rows {2tl, 2tl+1}.
// LDS buf[x]: 3 rows (local 0 = halo r0-1, 1 = r0, 2 = r0+1), XOR-swizzled.
// Step s reads buf[s&1], writes buf[(s+1)&1]. Halo comes from the LLC ring.
__global__ __launch_bounds__(256, 2)
void scan_kernel(bf16* __restrict__ lhLout, bf16* __restrict__ lhRout,
                 const ushort4* __restrict__ hmap2,
                 const bf16* __restrict__ WnL, const bf16* __restrict__ WnR,
                 const float* __restrict__ bL, const float* __restrict__ bR,
                 bf16* __restrict__ ring, unsigned* __restrict__ prodFlag,
                 unsigned* __restrict__ consFlag) {
  __shared__ __align__(16) bf16 buf[2][3 * 32 * 64];  // 2 x 12 KB
  const int blk = blockIdx.x;
  const int q = blk & 31, tl = blk >> 5;
  const bool right = (q & 1) != 0;
  const int b = q >> 1;
  const int r0 = tl * 2;
  const int t = threadIdx.x;
  const int dw = right ? 1 : -1;
  bf16* __restrict__ lout = right ? lhRout : lhLout;
  const bf16* __restrict__ Wn = right ? WnR : WnL;
  const float* __restrict__ bias = right ? bR : bL;
  const int wv = t >> 6, l = t & 63, l15 = l & 15, lq = l >> 4;
  const int c = wv * 16 + l15;  // channel this lane owns (gate-interleaved N)

  // zero buf[0] fully (step-0 state = 0) + buf[1] row0 (tl==0 halo stays 0)
#pragma unroll
  for (int i = 0; i < 3; ++i) ((bf16x8*)buf[0])[t + 256 * i] = bzero8();
  ((bf16x8*)buf[1])[t] = bzero8();

  // ---- loop-invariant registers ----
  bf16x8 bfrag[4][4];
#pragma unroll
  for (int g = 0; g < 4; ++g)
#pragma unroll
    for (int kk = 0; kk < 4; ++kk)
      bfrag[g][kk] = *(const bf16x8*)(Wn + (g * 64 + c) * 128 + kk * 32 + lq * 8);
  float bq[4];
#pragma unroll
  for (int g = 0; g < 4; ++g) bq[g] = bias[g * 64 + c];
  ushort4 hmp[4][4];
#pragma unroll
  for (int ms = 0; ms < 4; ++ms)
#pragma unroll
    for (int j = 0; j < 4; ++j) {
      int w = (ms & 1) * 16 + lq * 4 + j;
      size_t p = (size_t)((b * 32 + r0 + (ms >> 1)) * 32 + w);
      hmp[ms][j] = hmap2[p * 64 + c];
    }
  float lc_r[4][4];
#pragma unroll
  for (int ms = 0; ms < 4; ++ms)
#pragma unroll
    for (int j = 0; j < 4; ++j) lc_r[ms][j] = 0.0f;

  const unsigned* pBelow = prodFlag + (size_t)(blk - 32) * 32;
  const unsigned* cAbove = consFlag + (size_t)(blk + 32) * 32;
  unsigned* myProd = prodFlag + (size_t)blk * 32;
  unsigned* myCons = consFlag + (size_t)blk * 32;

  __syncthreads();

  for (int s = 0; s < 32; ++s) {
    bf16* curb = buf[s & 1];
    bf16* nxtb = buf[(s + 1) & 1];
    const bool consume = (tl > 0) && (s > 0);
    const bool publish = (tl < 15) && (s < 31);

    // ---- (1) acquire halo row (old r0-1) into curb row0 ----
    if (consume) {
      const unsigned tgt = (unsigned)s;  // below set flag = s after its step s-1
      while (__hip_atomic_load(pBelow, __ATOMIC_RELAXED, SCOPE_AGENT) < tgt)
        __builtin_amdgcn_s_sleep(1);
      const bf16* slotIn =
          ring + (size_t)((((s - 1) & 7) * 512) + (blk - 32)) * 2048;
      int w = t >> 3, c8 = t & 7;
      const unsigned long long* src =
          (const unsigned long long*)(slotIn + w * 64 + c8 * 8);
      unsigned long long d0 = __hip_atomic_load(src, __ATOMIC_RELAXED, SCOPE_AGENT);
      unsigned long long d1 = __hip_atomic_load(src + 1, __ATOMIC_RELAXED, SCOPE_AGENT);
      int off = (w * 128 + c8 * 16) ^ ((w & 7) << 4);
      *(unsigned long long*)((char*)curb + off) = d0;
      *(unsigned long long*)((char*)curb + off + 8) = d1;
    }
    // ---- ring-slot reuse guard (slot s&7 last consumed at consumer step s-7)
    if (publish && s >= 8) {
      const unsigned tgt = (unsigned)(s - 7);
      while (__hip_atomic_load(cAbove, __ATOMIC_RELAXED, SCOPE_AGENT) < tgt)
        __builtin_amdgcn_s_sleep(1);
    }
    __syncthreads();  // halo visible; curb complete

    // ---- (2) compute: 4 m-tiles; new rows 1,2 of nxtb; publish row 2 ----
    bf16* slotOut = ring + (size_t)(((s & 7) * 512) + blk) * 2048;
#pragma unroll
    for (int ms = 0; ms < 4; ++ms) {
      const int R = 1 + (ms >> 1);       // local new row
      const int wb_ = (ms & 1) * 16;
      const int wsrc = wb_ + l15 + dw;
      const bool oob = (unsigned)wsrc >= 32u;
      const int wc = wsrc & 31;
      f32x4 acc[4];
      const f32x4 fz = {0.f, 0.f, 0.f, 0.f};
#pragma unroll
      for (int g = 0; g < 4; ++g) acc[g] = fz;
#pragma unroll
      for (int kk = 0; kk < 4; ++kk) {
        const int srcr = (ms >> 1) + (kk >> 1);  // local old row
        const int c0 = (kk & 1) * 32 + lq * 8;
        int aoff = ((srcr * 32 + wc) * 128 + c0 * 2) ^ ((wc & 7) << 4);
        bf16x8 a = *(const bf16x8*)((const char*)curb + aoff);
        if (oob) a = bzero8();
#pragma unroll
        for (int g = 0; g < 4; ++g)
          acc[g] = __builtin_amdgcn_mfma_f32_16x16x32_bf16(a, bfrag[g][kk], acc[g], 0, 0, 0);
      }
#pragma unroll
      for (int j = 0; j < 4; ++j) {
        const int w = wb_ + lq * 4 + j;
        ushort4 hm = hmp[ms][j];
        float pre0 = acc[0][j] + bu2f(hm.x) + bq[0];
        float pre1 = acc[1][j] + bu2f(hm.y) + bq[1];
        float pre2 = acc[2][j] + bu2f(hm.z) + bq[2];
        float pre3 = acc[3][j] + bu2f(hm.w) + bq[3];
        float og = sigf(pre0), fg = sigf(pre1), ig = sigf(pre2), gg = sigf(pre3);
        float lcv = fg * lc_r[ms][j] + ig * gg;
        lc_r[ms][j] = lcv;
        bf16 vb = (bf16)(og * tanh_fast(lcv));
        int woff = ((R * 32 + w) * 128 + c * 2) ^ ((w & 7) << 4);
        *(bf16*)((char*)nxtb + woff) = vb;
        if (ms >= 2 && publish) {
          // pair adjacent channels (lanes l, l^1) into one dword, LLC store
          unsigned u = (unsigned)__builtin_bit_cast(unsigned short, vb);
          unsigned pv = (unsigned)__shfl_xor((int)u, 1);
          if ((l & 1) == 0) {
            unsigned dword = u | (pv << 16);
            __hip_atomic_store((unsigned*)(slotOut + w * 64 + (c & ~1)), dword,
                               __ATOMIC_RELAXED, SCOPE_AGENT);
          }
        }
      }
    }
    __syncthreads();  // drains vmcnt (publish stores at LLC) + LDS writes
    if (publish && t == 0)
      __hip_atomic_store(myProd, (unsigned)(s + 1), __ATOMIC_RELAXED, SCOPE_AGENT);
    if (consume && t == 64)
      __hip_atomic_store(myCons, (unsigned)s, __ATOMIC_RELAXED, SCOPE_AGENT);
  }

  // ---- final writeback: rows 1,2 of buf[0] (step 31 wrote buf[0]) ----
#pragma unroll
  for (int i = 0; i < 2; ++i) {
    int idx = t + 256 * i;  // [0,512)
    int R = 1 + (idx >> 8), rem = idx & 255;
    int w = rem >> 3, c8 = rem & 7;
    int off = ((R * 32 + w) * 128 + c8 * 16) ^ ((w & 7) << 4);
    bf16x8 v = *(const bf16x8*)((const char*)buf[0] + off);
    *(bf16x8*)(lout + (size_t)((b * 32 + r0 + R - 1) * 32 + w) * 64 + c8 * 8) = v;
  }
}

// ---------------- final: out = x + (lhL + shift_down(lhR)) @ w_skip^T + b ----------------
__global__ __launch_bounds__(256, 2)
void final_kernel(const float* __restrict__ x, const bf16* __restrict__ lhL,
                  const bf16* __restrict__ lhR, const bf16* __restrict__ Wn,
                  const float* __restrict__ b_skip, float* __restrict__ out) {
  __shared__ __align__(16) bf16 At[64 * 64];
  __shared__ __align__(16) float smemT[128 * 72];  // [o2][m], padded rows
  const int tile = blockIdx.x;
  const int b = tile >> 4, h0 = (tile & 15) << 1;
  const int t = threadIdx.x;
#pragma unroll
  for (int i = 0; i < 2; ++i) {
    int idx = t + 256 * i;  // [0,512)
    int m = idx >> 3, c8 = idx & 7;
    int h = h0 + (m >> 5), w = m & 31;
    size_t p = (size_t)(b * 32 + h) * 32 + w;
    bf16x8 vL = *(const bf16x8*)(lhL + p * 64 + c8 * 8);
    bf16x8 v;
    if (h > 0) {
      bf16x8 vR = *(const bf16x8*)(lhR + (p - 32) * 64 + c8 * 8);
#pragma unroll
      for (int e = 0; e < 8; ++e) v[e] = (bf16)((float)vL[e] + (float)vR[e]);
    } else {
      v = vL;
    }
    int kb = (c8 * 16) ^ ((m & 7) << 4);
    *(bf16x8*)((char*)At + m * 128 + kb) = v;
  }
  __syncthreads();
  const int wv = t >> 6, l = t & 63;
  const int l15 = l & 15, lq = l >> 4;
  const int c = wv * 16 + l15;
  bf16x8 bfrag[2][2];
#pragma unroll
  for (int g = 0; g < 2; ++g)
#pragma unroll
    for (int kk = 0; kk < 2; ++kk)
      bfrag[g][kk] = *(const bf16x8*)(Wn + (g * 64 + c) * 64 + kk * 32 + lq * 8);
  f32x4 acc[4][2];
  const f32x4 fz = {0.f, 0.f, 0.f, 0.f};
#pragma unroll
  for (int ms = 0; ms < 4; ++ms)
#pragma unroll
    for (int g = 0; g < 2; ++g) acc[ms][g] = fz;
#pragma unroll
  for (int kk = 0; kk < 2; ++kk) {
#pragma unroll
    for (int ms = 0; ms < 4; ++ms) {
      int m = ms * 16 + l15;
      int kb = ((kk * 32 + lq * 8) * 2) ^ ((m & 7) << 4);
      bf16x8 a = *(const bf16x8*)((const char*)At + m * 128 + kb);
#pragma unroll
      for (int g = 0; g < 2; ++g)
        acc[ms][g] =
            __builtin_amdgcn_mfma_f32_16x16x32_bf16(a, bfrag[g][kk], acc[ms][g], 0, 0, 0);
    }
  }
  float bsk[2];
#pragma unroll
  for (int g = 0; g < 2; ++g) bsk[g] = b_skip[g * 64 + c];
#pragma unroll
  for (int ms = 0; ms < 4; ++ms)
#pragma unroll
    for (int g = 0; g < 2; ++g)
#pragma unroll
      for (int j = 0; j < 4; ++j) {
        int m = ms * 16 + lq * 4 + j;
        int n = g * 64 + c;
        smemT[n * 72 + m] = acc[ms][g][j] + bsk[g];
      }
  __syncthreads();
  const float* xb = x + (size_t)(b * 128) * 1024 + h0 * 32;
  float* ob = out + (size_t)(b * 128) * 1024 + h0 * 32;
#pragma unroll
  for (int i = 0; i < 8; ++i) {
    int idx = t + 256 * i;  // [0,2048)
    int o2 = idx >> 4, m4 = idx & 15;
    f32x4 s = *(const f32x4*)(&smemT[o2 * 72 + m4 * 4]);
    f32x4 xv = *(const f32x4*)(xb + (size_t)o2 * 1024 + m4 * 4);
#pragma unroll
    for (int e = 0; e < 4; ++e) s[e] += xv[e];
    *(f32x4*)(ob + (size_t)o2 * 1024 + m4 * 4) = s;
  }
}

extern "C" void kernel_launch(void* const* d_in, const int* in_sizes, int n_in,
                              void* d_out, int out_size, void* d_ws, size_t ws_size,
                              hipStream_t stream) {
  const float* x       = (const float*)d_in[0];
  const float* w_i2s   = (const float*)d_in[1];
  const float* w_left  = (const float*)d_in[2];
  const float* b_left  = (const float*)d_in[3];
  const float* w_right = (const float*)d_in[4];
  const float* b_right = (const float*)d_in[5];
  const float* w_skip  = (const float*)d_in[6];
  const float* b_skip  = (const float*)d_in[7];
  float* out = (float*)d_out;
  char* ws = (char*)d_ws;

  // ws layout (bytes); total ~29.8 MB
  bf16*     lhL   = (bf16*)(ws + 0x0000000);     // 2 MB (fully written by scan)
  bf16*     lhR   = (bf16*)(ws + 0x0200000);     // 2 MB
  ushort4*  hmap2 = (ushort4*)(ws + 0x0400000);  // 8 MB
  bf16*     ring  = (bf16*)(ws + 0x0C00000);     // 16 MB (8 slots x 512 x 4KB)
  unsigned* prodF = (unsigned*)(ws + 0x1C00000); // 64 KB (zeroed)
  unsigned* consF = (unsigned*)(ws + 0x1C10000); // 64 KB (zeroed)
  bf16*     WnI   = (bf16*)(ws + 0x1C20000);     // 64 KB
  bf16*     WnL   = (bf16*)(ws + 0x1C30000);
  bf16*     WnR   = (bf16*)(ws + 0x1C40000);
  bf16*     WnS   = (bf16*)(ws + 0x1C50000);

  // zero only the sync flags (128 KB) -- ring is flag-guarded
  hipMemsetAsync(ws + 0x1C00000, 0, 0x20000, stream);
  prep_kernel<<<128, 256, 0, stream>>>(w_i2s, w_left, w_right, w_skip, WnI, WnL, WnR, WnS);
  hmap_kernel<<<256, 256, 0, stream>>>(x, WnI, hmap2);
  scan_kernel<<<512, 256, 0, stream>>>(lhL, lhR, hmap2, WnL, WnR,
                                       b_left, b_right, ring, prodF, consF);
  final_kernel<<<256, 256, 0, stream>>>(x, lhL, lhR, WnS, b_skip, out);
}

// Round 9
// 176.767 us; speedup vs baseline: 3.0105x; 1.0552x over previous
//
#include <hip/hip_runtime.h>

// BiLSTM (diagonal, PixelRNN-style) on MI355X.
// R8: persistent scan (R7 protocol) + intra-step pipeline: phase A computes the
// own-top row (no halo needed) and publishes it IMMEDIATELY; phase B spins for
// the halo and computes the dependent row. The LLC ring round-trip now overlaps
// compute instead of sitting on the wavefront critical path. Epilogue uses a
// fused-rcp formulation (8 trans/px-ch instead of 10).

using bf16   = __bf16;
using bf16x8 = __attribute__((ext_vector_type(8))) __bf16;
using f32x4  = __attribute__((ext_vector_type(4))) float;

#define SCOPE_AGENT __HIP_MEMORY_SCOPE_AGENT

__device__ __forceinline__ bf16x8 bzero8() {
  bf16x8 v;
#pragma unroll
  for (int e = 0; e < 8; ++e) v[e] = (bf16)0.0f;
  return v;
}
__device__ __forceinline__ unsigned short f2bu(float f) {
  bf16 b = (bf16)f;
  return __builtin_bit_cast(unsigned short, b);
}
__device__ __forceinline__ float bu2f(unsigned short u) {
  return __uint_as_float(((unsigned)u) << 16);
}
__device__ __forceinline__ float sigf(float x) {
  return __builtin_amdgcn_rcpf(1.0f + __expf(-x));
}
__device__ __forceinline__ float tanh_fast(float x) {
  return 2.0f * __builtin_amdgcn_rcpf(1.0f + __expf(-2.0f * x)) - 1.0f;
}

// ---------------- prep: weights -> bf16, [n][k] layouts ----------------
__global__ void prep_kernel(const float* __restrict__ w_i2s,
                            const float* __restrict__ w_left,
                            const float* __restrict__ w_right,
                            const float* __restrict__ w_skip,
                            bf16* __restrict__ WnI, bf16* __restrict__ WnL,
                            bf16* __restrict__ WnR, bf16* __restrict__ WnS) {
  int t = blockIdx.x * 256 + threadIdx.x;
  if (t < 32768) {
    WnI[t] = (bf16)w_i2s[t];  // [256][128] o-major == desired [n][k]
    int o = t >> 7, k = t & 127;
    // k<64: tap0 (h-1, w+-1) -> w[:,:,0]; k>=64: tap1 (h, w+-1) -> w[:,:,1]
    int src = (k < 64) ? (o * 128 + k * 2) : (o * 128 + (k - 64) * 2 + 1);
    WnL[t] = (bf16)w_left[src];
    WnR[t] = (bf16)w_right[src];
    if (t < 8192) WnS[t] = (bf16)w_skip[t];  // [128][64]
  }
}

// ------- hmap2 = pack(x @ w_i2s^T) : [p][c] ushort4 (4 gates, bf16 bits) -------
__global__ __launch_bounds__(256, 2)
void hmap_kernel(const float* __restrict__ x, const bf16* __restrict__ Wn,
                 ushort4* __restrict__ hmap2) {
  __shared__ __align__(16) bf16 At[64 * 128];  // XOR-swizzled
  const int tile = blockIdx.x;  // 256 tiles: 64 px each (2 rows of one batch)
  const int b = tile >> 4, h0 = (tile & 15) << 1;
  const int t = threadIdx.x;
  const float* xb = x + (size_t)(b * 128) * 1024 + h0 * 32;
#pragma unroll
  for (int i = 0; i < 8; ++i) {
    int idx = t + 256 * i;          // [0,2048)
    int cc = idx >> 4, m4 = idx & 15;
    f32x4 v = *(const f32x4*)(xb + (size_t)cc * 1024 + m4 * 4);
#pragma unroll
    for (int e = 0; e < 4; ++e) {
      int m = m4 * 4 + e;
      int kb = (cc * 2) ^ ((m & 7) << 4);
      *(bf16*)((char*)At + m * 256 + kb) = (bf16)v[e];
    }
  }
  __syncthreads();
  const int wv = t >> 6, l = t & 63;
  const int l15 = l & 15, lq = l >> 4;
  const int c = wv * 16 + l15;
  bf16x8 bfrag[4][4];
#pragma unroll
  for (int q = 0; q < 4; ++q)
#pragma unroll
    for (int kk = 0; kk < 4; ++kk)
      bfrag[q][kk] = *(const bf16x8*)(Wn + (q * 64 + c) * 128 + kk * 32 + lq * 8);
  f32x4 acc[4][4];
  const f32x4 fz = {0.f, 0.f, 0.f, 0.f};
#pragma unroll
  for (int ms = 0; ms < 4; ++ms)
#pragma unroll
    for (int q = 0; q < 4; ++q) acc[ms][q] = fz;
#pragma unroll
  for (int kk = 0; kk < 4; ++kk) {
#pragma unroll
    for (int ms = 0; ms < 4; ++ms) {
      int m = ms * 16 + l15;
      int kb = ((kk * 32 + lq * 8) * 2) ^ ((m & 7) << 4);
      bf16x8 a = *(const bf16x8*)((const char*)At + m * 256 + kb);
#pragma unroll
      for (int q = 0; q < 4; ++q)
        acc[ms][q] =
            __builtin_amdgcn_mfma_f32_16x16x32_bf16(a, bfrag[q][kk], acc[ms][q], 0, 0, 0);
    }
  }
  const int pix0 = tile * 64;
#pragma unroll
  for (int ms = 0; ms < 4; ++ms)
#pragma unroll
    for (int j = 0; j < 4; ++j) {
      int p = pix0 + ms * 16 + lq * 4 + j;
      ushort4 hv;
      hv.x = f2bu(acc[ms][0][j]);
      hv.y = f2bu(acc[ms][1][j]);
      hv.z = f2bu(acc[ms][2][j]);
      hv.w = f2bu(acc[ms][3][j]);
      hmap2[(size_t)p * 64 + c] = hv;
    }
}

// ---------------- persistent scan: all 32 steps ----------------
// blk = tl*32 + q, q = batch*2 + stream. Block owns rows {2tl, 2tl+1}.
// LDS buf[x]: 3 rows (local 0 = halo r0-1, 1 = r0, 2 = r0+1), XOR-swizzled.
// Step s: phase A computes row r0+1 (ms 2,3; no halo) and publishes it;
// phase B spins for the halo and computes row r0 (ms 0,1).
__global__ __launch_bounds__(256, 2)
void scan_kernel(bf16* __restrict__ lhLout, bf16* __restrict__ lhRout,
                 const ushort4* __restrict__ hmap2,
                 const bf16* __restrict__ WnL, const bf16* __restrict__ WnR,
                 const float* __restrict__ bL, const float* __restrict__ bR,
                 bf16* __restrict__ ring, unsigned* __restrict__ prodFlag,
                 unsigned* __restrict__ consFlag) {
  __shared__ __align__(16) bf16 buf[2][3 * 32 * 64];  // 2 x 12 KB
  const int blk = blockIdx.x;
  const int q = blk & 31, tl = blk >> 5;
  const bool right = (q & 1) != 0;
  const int b = q >> 1;
  const int r0 = tl * 2;
  const int t = threadIdx.x;
  const int dw = right ? 1 : -1;
  bf16* __restrict__ lout = right ? lhRout : lhLout;
  const bf16* __restrict__ Wn = right ? WnR : WnL;
  const float* __restrict__ bias = right ? bR : bL;
  const int wv = t >> 6, l = t & 63, l15 = l & 15, lq = l >> 4;
  const int c = wv * 16 + l15;  // channel this lane owns (gate-interleaved N)

  // zero buf[0] fully (step-0 state = 0) + buf[1] row0 (tl==0 halo stays 0)
#pragma unroll
  for (int i = 0; i < 3; ++i) ((bf16x8*)buf[0])[t + 256 * i] = bzero8();
  ((bf16x8*)buf[1])[t] = bzero8();

  // ---- loop-invariant registers ----
  bf16x8 bfrag[4][4];
#pragma unroll
  for (int g = 0; g < 4; ++g)
#pragma unroll
    for (int kk = 0; kk < 4; ++kk)
      bfrag[g][kk] = *(const bf16x8*)(Wn + (g * 64 + c) * 128 + kk * 32 + lq * 8);
  float bq[4];
#pragma unroll
  for (int g = 0; g < 4; ++g) bq[g] = bias[g * 64 + c];
  ushort4 hmp[4][4];
#pragma unroll
  for (int ms = 0; ms < 4; ++ms)
#pragma unroll
    for (int j = 0; j < 4; ++j) {
      int w = (ms & 1) * 16 + lq * 4 + j;
      size_t p = (size_t)((b * 32 + r0 + (ms >> 1)) * 32 + w);
      hmp[ms][j] = hmap2[p * 64 + c];
    }
  float lc_r[4][4];
#pragma unroll
  for (int ms = 0; ms < 4; ++ms)
#pragma unroll
    for (int j = 0; j < 4; ++j) lc_r[ms][j] = 0.0f;

  const unsigned* pBelow = prodFlag + (size_t)(blk - 32) * 32;
  const unsigned* cAbove = consFlag + (size_t)(blk + 32) * 32;
  unsigned* myProd = prodFlag + (size_t)blk * 32;
  unsigned* myCons = consFlag + (size_t)blk * 32;

  __syncthreads();

  for (int s = 0; s < 32; ++s) {
    bf16* curb = buf[s & 1];
    bf16* nxtb = buf[(s + 1) & 1];
    const bool consume = (tl > 0) && (s > 0);
    const bool publish = (tl < 15) && (s < 31);
    bf16* slotOut = ring + (size_t)(((s & 7) * 512) + blk) * 2048;

    // ---- ring-slot reuse guard (steady state: never blocks) ----
    if (publish && s >= 8) {
      const unsigned tgt = (unsigned)(s - 7);
      while (__hip_atomic_load(cAbove, __ATOMIC_RELAXED, SCOPE_AGENT) < tgt)
        __builtin_amdgcn_s_sleep(1);
    }

    // ---- phase A: own-top tiles (ms 2,3; read curb rows 1,2) + publish ----
#pragma unroll
    for (int ms = 2; ms < 4; ++ms) {
      const int wb_ = (ms & 1) * 16;
      const int wsrc = wb_ + l15 + dw;
      const bool oob = (unsigned)wsrc >= 32u;
      const int wc = wsrc & 31;
      f32x4 acc[4];
      const f32x4 fz = {0.f, 0.f, 0.f, 0.f};
#pragma unroll
      for (int g = 0; g < 4; ++g) acc[g] = fz;
#pragma unroll
      for (int kk = 0; kk < 4; ++kk) {
        const int srcr = 1 + (kk >> 1);
        const int c0 = (kk & 1) * 32 + lq * 8;
        int aoff = ((srcr * 32 + wc) * 128 + c0 * 2) ^ ((wc & 7) << 4);
        bf16x8 a = *(const bf16x8*)((const char*)curb + aoff);
        if (oob) a = bzero8();
#pragma unroll
        for (int g = 0; g < 4; ++g)
          acc[g] = __builtin_amdgcn_mfma_f32_16x16x32_bf16(a, bfrag[g][kk], acc[g], 0, 0, 0);
      }
#pragma unroll
      for (int j = 0; j < 4; ++j) {
        const int w = wb_ + lq * 4 + j;
        ushort4 hm = hmp[ms][j];
        float e0 = __expf(-(acc[0][j] + bu2f(hm.x) + bq[0]));
        float e1 = __expf(-(acc[1][j] + bu2f(hm.y) + bq[1]));
        float e2 = __expf(-(acc[2][j] + bu2f(hm.z) + bq[2]));
        float e3 = __expf(-(acc[3][j] + bu2f(hm.w) + bq[3]));
        float fg = __builtin_amdgcn_rcpf(1.0f + e1);
        float igg = __builtin_amdgcn_rcpf((1.0f + e2) * (1.0f + e3));
        float lcv = fg * lc_r[ms][j] + igg;
        lc_r[ms][j] = lcv;
        float ey = __expf(-2.0f * lcv);
        float lh = (1.0f - ey) * __builtin_amdgcn_rcpf((1.0f + e0) * (1.0f + ey));
        bf16 vb = (bf16)lh;
        int woff = ((2 * 32 + w) * 128 + c * 2) ^ ((w & 7) << 4);
        *(bf16*)((char*)nxtb + woff) = vb;
        if (publish) {
          unsigned u = (unsigned)__builtin_bit_cast(unsigned short, vb);
          unsigned pv = (unsigned)__shfl_xor((int)u, 1);
          if ((l & 1) == 0) {
            unsigned dword = u | (pv << 16);
            __hip_atomic_store((unsigned*)(slotOut + w * 64 + (c & ~1)), dword,
                               __ATOMIC_RELAXED, SCOPE_AGENT);
          }
        }
      }
    }
    __syncthreads();  // drains ring stores (vmcnt) + nxtb row-2 LDS writes
    if (publish && t == 0)
      __hip_atomic_store(myProd, (unsigned)(s + 1), __ATOMIC_RELAXED, SCOPE_AGENT);

    // ---- phase B: acquire halo into curb row 0, then dependent tiles ----
    if (consume) {
      const unsigned tgt = (unsigned)s;  // below set flag=s in its step s-1 phase A
      while (__hip_atomic_load(pBelow, __ATOMIC_RELAXED, SCOPE_AGENT) < tgt)
        __builtin_amdgcn_s_sleep(1);
      const bf16* slotIn =
          ring + (size_t)((((s - 1) & 7) * 512) + (blk - 32)) * 2048;
      int w = t >> 3, c8 = t & 7;
      const unsigned long long* src =
          (const unsigned long long*)(slotIn + w * 64 + c8 * 8);
      unsigned long long d0 = __hip_atomic_load(src, __ATOMIC_RELAXED, SCOPE_AGENT);
      unsigned long long d1 = __hip_atomic_load(src + 1, __ATOMIC_RELAXED, SCOPE_AGENT);
      int off = (w * 128 + c8 * 16) ^ ((w & 7) << 4);
      *(unsigned long long*)((char*)curb + off) = d0;
      *(unsigned long long*)((char*)curb + off + 8) = d1;
    }
    __syncthreads();  // halo visible (vmcnt drained per wave before barrier)
    if (consume && t == 0)
      __hip_atomic_store(myCons, (unsigned)s, __ATOMIC_RELAXED, SCOPE_AGENT);

#pragma unroll
    for (int ms = 0; ms < 2; ++ms) {
      const int wb_ = (ms & 1) * 16;
      const int wsrc = wb_ + l15 + dw;
      const bool oob = (unsigned)wsrc >= 32u;
      const int wc = wsrc & 31;
      f32x4 acc[4];
      const f32x4 fz = {0.f, 0.f, 0.f, 0.f};
#pragma unroll
      for (int g = 0; g < 4; ++g) acc[g] = fz;
#pragma unroll
      for (int kk = 0; kk < 4; ++kk) {
        const int srcr = kk >> 1;
        const int c0 = (kk & 1) * 32 + lq * 8;
        int aoff = ((srcr * 32 + wc) * 128 + c0 * 2) ^ ((wc & 7) << 4);
        bf16x8 a = *(const bf16x8*)((const char*)curb + aoff);
        if (oob) a = bzero8();
#pragma unroll
        for (int g = 0; g < 4; ++g)
          acc[g] = __builtin_amdgcn_mfma_f32_16x16x32_bf16(a, bfrag[g][kk], acc[g], 0, 0, 0);
      }
#pragma unroll
      for (int j = 0; j < 4; ++j) {
        const int w = wb_ + lq * 4 + j;
        ushort4 hm = hmp[ms][j];
        float e0 = __expf(-(acc[0][j] + bu2f(hm.x) + bq[0]));
        float e1 = __expf(-(acc[1][j] + bu2f(hm.y) + bq[1]));
        float e2 = __expf(-(acc[2][j] + bu2f(hm.z) + bq[2]));
        float e3 = __expf(-(acc[3][j] + bu2f(hm.w) + bq[3]));
        float fg = __builtin_amdgcn_rcpf(1.0f + e1);
        float igg = __builtin_amdgcn_rcpf((1.0f + e2) * (1.0f + e3));
        float lcv = fg * lc_r[ms][j] + igg;
        lc_r[ms][j] = lcv;
        float ey = __expf(-2.0f * lcv);
        float lh = (1.0f - ey) * __builtin_amdgcn_rcpf((1.0f + e0) * (1.0f + ey));
        int woff = ((1 * 32 + w) * 128 + c * 2) ^ ((w & 7) << 4);
        *(bf16*)((char*)nxtb + woff) = (bf16)lh;
      }
    }
    __syncthreads();  // end of step: nxtb complete before next phase A reads
  }

  // ---- final writeback: rows 1,2 of buf[0] (step 31 wrote buf[0]) ----
#pragma unroll
  for (int i = 0; i < 2; ++i) {
    int idx = t + 256 * i;  // [0,512)
    int R = 1 + (idx >> 8), rem = idx & 255;
    int w = rem >> 3, c8 = rem & 7;
    int off = ((R * 32 + w) * 128 + c8 * 16) ^ ((w & 7) << 4);
    bf16x8 v = *(const bf16x8*)((const char*)buf[0] + off);
    *(bf16x8*)(lout + (size_t)((b * 32 + r0 + R - 1) * 32 + w) * 64 + c8 * 8) = v;
  }
}

// ---------------- final: out = x + (lhL + shift_down(lhR)) @ w_skip^T + b ----------------
__global__ __launch_bounds__(256, 2)
void final_kernel(const float* __restrict__ x, const bf16* __restrict__ lhL,
                  const bf16* __restrict__ lhR, const bf16* __restrict__ Wn,
                  const float* __restrict__ b_skip, float* __restrict__ out) {
  __shared__ __align__(16) bf16 At[64 * 64];
  __shared__ __align__(16) float smemT[128 * 72];  // [o2][m], padded rows
  const int tile = blockIdx.x;
  const int b = tile >> 4, h0 = (tile & 15) << 1;
  const int t = threadIdx.x;
#pragma unroll
  for (int i = 0; i < 2; ++i) {
    int idx = t + 256 * i;  // [0,512)
    int m = idx >> 3, c8 = idx & 7;
    int h = h0 + (m >> 5), w = m & 31;
    size_t p = (size_t)(b * 32 + h) * 32 + w;
    bf16x8 vL = *(const bf16x8*)(lhL + p * 64 + c8 * 8);
    bf16x8 v;
    if (h > 0) {
      bf16x8 vR = *(const bf16x8*)(lhR + (p - 32) * 64 + c8 * 8);
#pragma unroll
      for (int e = 0; e < 8; ++e) v[e] = (bf16)((float)vL[e] + (float)vR[e]);
    } else {
      v = vL;
    }
    int kb = (c8 * 16) ^ ((m & 7) << 4);
    *(bf16x8*)((char*)At + m * 128 + kb) = v;
  }
  __syncthreads();
  const int wv = t >> 6, l = t & 63;
  const int l15 = l & 15, lq = l >> 4;
  const int c = wv * 16 + l15;
  bf16x8 bfrag[2][2];
#pragma unroll
  for (int g = 0; g < 2; ++g)
#pragma unroll
    for (int kk = 0; kk < 2; ++kk)
      bfrag[g][kk] = *(const bf16x8*)(Wn + (g * 64 + c) * 64 + kk * 32 + lq * 8);
  f32x4 acc[4][2];
  const f32x4 fz = {0.f, 0.f, 0.f, 0.f};
#pragma unroll
  for (int ms = 0; ms < 4; ++ms)
#pragma unroll
    for (int g = 0; g < 2; ++g) acc[ms][g] = fz;
#pragma unroll
  for (int kk = 0; kk < 2; ++kk) {
#pragma unroll
    for (int ms = 0; ms < 4; ++ms) {
      int m = ms * 16 + l15;
      int kb = ((kk * 32 + lq * 8) * 2) ^ ((m & 7) << 4);
      bf16x8 a = *(const bf16x8*)((const char*)At + m * 128 + kb);
#pragma unroll
      for (int g = 0; g < 2; ++g)
        acc[ms][g] =
            __builtin_amdgcn_mfma_f32_16x16x32_bf16(a, bfrag[g][kk], acc[ms][g], 0, 0, 0);
    }
  }
  float bsk[2];
#pragma unroll
  for (int g = 0; g < 2; ++g) bsk[g] = b_skip[g * 64 + c];
#pragma unroll
  for (int ms = 0; ms < 4; ++ms)
#pragma unroll
    for (int g = 0; g < 2; ++g)
#pragma unroll
      for (int j = 0; j < 4; ++j) {
        int m = ms * 16 + lq * 4 + j;
        int n = g * 64 + c;
        smemT[n * 72 + m] = acc[ms][g][j] + bsk[g];
      }
  __syncthreads();
  const float* xb = x + (size_t)(b * 128) * 1024 + h0 * 32;
  float* ob = out + (size_t)(b * 128) * 1024 + h0 * 32;
#pragma unroll
  for (int i = 0; i < 8; ++i) {
    int idx = t + 256 * i;  // [0,2048)
    int o2 = idx >> 4, m4 = idx & 15;
    f32x4 s = *(const f32x4*)(&smemT[o2 * 72 + m4 * 4]);
    f32x4 xv = *(const f32x4*)(xb + (size_t)o2 * 1024 + m4 * 4);
#pragma unroll
    for (int e = 0; e < 4; ++e) s[e] += xv[e];
    *(f32x4*)(ob + (size_t)o2 * 1024 + m4 * 4) = s;
  }
}

extern "C" void kernel_launch(void* const* d_in, const int* in_sizes, int n_in,
                              void* d_out, int out_size, void* d_ws, size_t ws_size,
                              hipStream_t stream) {
  const float* x       = (const float*)d_in[0];
  const float* w_i2s   = (const float*)d_in[1];
  const float* w_left  = (const float*)d_in[2];
  const float* b_left  = (const float*)d_in[3];
  const float* w_right = (const float*)d_in[4];
  const float* b_right = (const float*)d_in[5];
  const float* w_skip  = (const float*)d_in[6];
  const float* b_skip  = (const float*)d_in[7];
  float* out = (float*)d_out;
  char* ws = (char*)d_ws;

  // ws layout (bytes); total ~29.8 MB
  bf16*     lhL   = (bf16*)(ws + 0x0000000);     // 2 MB (fully written by scan)
  bf16*     lhR   = (bf16*)(ws + 0x0200000);     // 2 MB
  ushort4*  hmap2 = (ushort4*)(ws + 0x0400000);  // 8 MB
  bf16*     ring  = (bf16*)(ws + 0x0C00000);     // 16 MB (8 slots x 512 x 4KB)
  unsigned* prodF = (unsigned*)(ws + 0x1C00000); // 64 KB (zeroed)
  unsigned* consF = (unsigned*)(ws + 0x1C10000); // 64 KB (zeroed)
  bf16*     WnI   = (bf16*)(ws + 0x1C20000);     // 64 KB
  bf16*     WnL   = (bf16*)(ws + 0x1C30000);
  bf16*     WnR   = (bf16*)(ws + 0x1C40000);
  bf16*     WnS   = (bf16*)(ws + 0x1C50000);

  // zero only the sync flags (128 KB) -- ring is flag-guarded
  hipMemsetAsync(ws + 0x1C00000, 0, 0x20000, stream);
  prep_kernel<<<128, 256, 0, stream>>>(w_i2s, w_left, w_right, w_skip, WnI, WnL, WnR, WnS);
  hmap_kernel<<<256, 256, 0, stream>>>(x, WnI, hmap2);
  scan_kernel<<<512, 256, 0, stream>>>(lhL, lhR, hmap2, WnL, WnR,
                                       b_left, b_right, ring, prodF, consF);
  final_kernel<<<256, 256, 0, stream>>>(x, lhL, lhR, WnS, b_skip, out);
}